// Round 10
// baseline (155.189 us; speedup 1.0000x reference)
//
#include <hip/hip_runtime.h>
#include <stdint.h>

#define NM 2048

typedef _Float16 f16;
typedef __attribute__((ext_vector_type(8))) _Float16 half8;
typedef __attribute__((ext_vector_type(4))) float float4v;

// Fragment-tiled layout: element (m,k) lives at
//   ((m/16)*256 + k/8)*128 + (m%16)*8 + k%8
// so a wave's 16x32 MFMA fragment (rows l15, k-chunk qq) is ONE contiguous,
// coalesced 1KB region: addr = base + lane*8 halfs.
__device__ __forceinline__ size_t toff(int m, int k) {
    return ((size_t)((m >> 4) * 256 + (k >> 3)) << 7) + ((m & 15) << 3) + (k & 7);
}

// X = A - A^T -> f16, written in fragment-tiled layout
__global__ void skew_f16_kernel(const float* __restrict__ A, f16* __restrict__ X) {
    __shared__ float t[32][33];
    const int bx = blockIdx.x * 32, by = blockIdx.y * 32;
    const int tx = threadIdx.x, ty = threadIdx.y;
    #pragma unroll
    for (int r = 0; r < 32; r += 8)
        t[ty + r][tx] = A[(size_t)(bx + ty + r) * NM + by + tx];
    __syncthreads();
    #pragma unroll
    for (int r = 0; r < 32; r += 8) {
        const int i = by + ty + r, j = bx + tx;
        X[toff(i, j)] = (f16)(A[(size_t)i * NM + j] - t[tx][ty + r]);
    }
}

// Degree-4 Paterson-Stockmeyer, two fused-epilogue GEMMs (tiled operands):
//   MODE 0: A=BT=X -> v = -(A*BT^T) = X2. Writes X2 (tiled) and
//           CT = 256*C^T (tiled): CT(row,col) = 256*(v/24 - X(row,col)/6).
//   MODE 1: A=X2, BT=CT -> v = 256*(X2*C). OUT = I + X + X2/2 + v/256 (fp32, row-major).
// Core: NO-LDS direct-to-VGPR K-loop. Block = 128 thr = 2 waves on one 64x64
// tile, split-K (wave kh does k in [kh*1024, kh*1024+1024)). Each k-step (32 k):
// 8 coalesced 1KB global_load_dwordx4 (4 A-frags + 4 B-frags) -> VGPR, 16 MFMA.
// 4-deep frag buffers, prefetch s+3 (~24 loads in flight) -> compiler emits
// fine-grained vmcnt; ZERO barriers in the loop. Grid 1024 -> 4 blk/CU ->
// 2 waves/SIMD. K-halves merged once via 17KB LDS at the end.
// NOTE: prefetch wraps 3 sets past the K range -> reads up to ~3KB into the
// next ws slot (allocated; values never consumed; benign).
template <int MODE>
__global__ __launch_bounds__(128, 2) void gemm_dv_kernel(
    const f16* __restrict__ Ap, const f16* __restrict__ BT,
    const f16* __restrict__ Xp, f16* __restrict__ X2p,
    f16* __restrict__ CTp, float* __restrict__ OUT) {
    __shared__ __align__(16) float mbuf[4352];   // 64 cols x stride-68 floats

    const int tid = threadIdx.x;
    const int kh = tid >> 6;          // wave 0: k-low + epilogue; wave 1: k-high
    const int lane = tid & 63;
    const int l15 = lane & 15, qq = lane >> 4;

    // XCD swizzle: 32x32 tile grid; each XCD gets an 8x16 rectangle.
    const int bid = blockIdx.x;
    const int xcd = bid & 7, li = bid >> 3;
    const int by = (xcd >> 1) * 8 + (li >> 4);
    const int bx = (xcd & 1) * 16 + (li & 15);
    const int rowBase = by * 64, colBase = bx * 64;

    // Next-set fragment pointers; one set = 4 A-frags + 4 B-frags (32 k).
    const f16* pa[4];
    const f16* pb[4];
    #pragma unroll
    for (int r = 0; r < 4; ++r) {
        pa[r] = Ap + ((size_t)((by * 4 + r) * 256 + kh * 128) << 7) + lane * 8;
        pb[r] = BT + ((size_t)((bx * 4 + r) * 256 + kh * 128) << 7) + lane * 8;
    }

    half8 abuf[4][4], bbuf[4][4];
    auto loadset = [&](int buf) {
        #pragma unroll
        for (int r = 0; r < 4; ++r) {
            abuf[buf][r] = *(const half8*)pa[r];
            bbuf[buf][r] = *(const half8*)pb[r];
            pa[r] += 512;   // 4 k-chunks x 128 halfs
            pb[r] += 512;
        }
    };

    float4v acc[4][4];
    #pragma unroll
    for (int r = 0; r < 4; ++r)
        #pragma unroll
        for (int c = 0; c < 4; ++c)
            acc[r][c] = (float4v){0.f, 0.f, 0.f, 0.f};

    loadset(0);
    loadset(1);
    loadset(2);

    #pragma unroll 4
    for (int s = 0; s < 32; ++s) {
        loadset((s + 3) & 3);         // wrapped prefetch (final 3 sets unused)
        const int b = s & 3;
        #pragma unroll
        for (int r = 0; r < 4; ++r)
            #pragma unroll
            for (int c = 0; c < 4; ++c)
                acc[r][c] = __builtin_amdgcn_mfma_f32_16x16x32_f16(
                    abuf[b][r], bbuf[b][c], acc[r][c], 0, 0, 0);
    }

    // K-merge: wave 1 dumps acc to LDS; wave 0 adds and runs the epilogue.
    if (kh == 1) {
        #pragma unroll
        for (int r = 0; r < 4; ++r)
            #pragma unroll
            for (int c = 0; c < 4; ++c)
                *(float4v*)&mbuf[(c * 16 + l15) * 68 + r * 16 + qq * 4] = acc[r][c];
    }
    __syncthreads();
    if (kh == 0) {
        #pragma unroll
        for (int r = 0; r < 4; ++r)
            #pragma unroll
            for (int c = 0; c < 4; ++c)
                acc[r][c] += *(const float4v*)&mbuf[(c * 16 + l15) * 68 + r * 16 + qq * 4];

        // C/D layout: col = lane&15, row = (lane>>4)*4 + reg
        #pragma unroll
        for (int r = 0; r < 4; ++r)
            #pragma unroll
            for (int c = 0; c < 4; ++c)
                #pragma unroll
                for (int g = 0; g < 4; ++g) {
                    const int row = rowBase + r * 16 + qq * 4 + g;
                    const int col = colBase + c * 16 + l15;
                    const size_t tix = toff(row, col);
                    float v = acc[r][c][g];
                    if (MODE == 0) {
                        v = -v;  // B = (X)^T = -X -> product = -X^2
                        const float x = (float)Xp[tix];
                        X2p[tix] = (f16)v;
                        CTp[tix] = (f16)(v * (256.0f / 24.0f) - x * (256.0f / 6.0f));
                    } else {
                        const float x = (float)Xp[tix];
                        const float x2 = (float)X2p[tix];
                        float o = x + 0.5f * x2 + v * (1.0f / 256.0f);
                        if (row == col) o += 1.0f;
                        OUT[(size_t)row * NM + col] = o;
                    }
                }
    }
}

extern "C" void kernel_launch(void* const* d_in, const int* in_sizes, int n_in,
                              void* d_out, int out_size, void* d_ws, size_t ws_size,
                              hipStream_t stream) {
    const float* A = (const float*)d_in[0];
    float* out = (float*)d_out;
    const size_t NN = (size_t)NM * NM;

    // ws: 3 tiled f16 planes (25.2 MB of 33.6 MB); 4th slot absorbs prefetch
    // overrun. d_out only written, never read.
    f16* X  = (f16*)d_ws;
    f16* X2 = X + NN;
    f16* CT = X2 + NN;

    dim3 tb(32, 8);
    dim3 tg(NM / 32, NM / 32);

    // exp(S) ~= T4(S) = (I + X + X2/2) + X2*C,  C = X/6 + X2/24.
    // 1) X = A - A^T (tiled)
    skew_f16_kernel<<<tg, tb, 0, stream>>>(A, X);
    // 2) X2 = X*X; epilogue also emits CT = 256*C^T (both tiled)
    gemm_dv_kernel<0><<<1024, 128, 0, stream>>>(X, X, X, X2, CT, nullptr);
    // 3) Y = X2*C; epilogue emits OUT = I + X + X2/2 + Y (fp32 row-major)
    gemm_dv_kernel<1><<<1024, 128, 0, stream>>>(X2, CT, X, X2, nullptr, out);
}

// Round 11
// 153.887 us; speedup vs baseline: 1.0085x; 1.0085x over previous
//
#include <hip/hip_runtime.h>
#include <stdint.h>

#define NM 2048

typedef _Float16 f16;
typedef __attribute__((ext_vector_type(8))) _Float16 half8;
typedef __attribute__((ext_vector_type(4))) float float4v;

// X = A - A^T -> f16 (exactly skew; |X| <~ 0.1)
__global__ void skew_f16_kernel(const float* __restrict__ A, f16* __restrict__ X) {
    __shared__ float t[32][33];
    const int bx = blockIdx.x * 32, by = blockIdx.y * 32;
    const int tx = threadIdx.x, ty = threadIdx.y;
    #pragma unroll
    for (int r = 0; r < 32; r += 8)
        t[ty + r][tx] = A[(size_t)(bx + ty + r) * NM + by + tx];
    __syncthreads();
    #pragma unroll
    for (int r = 0; r < 32; r += 8) {
        const int i = by + ty + r, j = bx + tx;
        X[(size_t)i * NM + j] = (f16)(A[(size_t)i * NM + j] - t[tx][ty + r]);
    }
}

// X2 = P1 + P2, in-place over P1
__global__ void sum2_kernel(f16* __restrict__ P1, const f16* __restrict__ P2) {
    const int base = (blockIdx.x * 256 + threadIdx.x) * 8;
    half8 a = *(const half8*)&P1[base];
    half8 b = *(const half8*)&P2[base];
    half8 o;
    #pragma unroll
    for (int j = 0; j < 8; ++j) o[j] = (f16)((float)a[j] + (float)b[j]);
    *(half8*)&P1[base] = o;
}

// OUT += X3 / 6
__global__ void addx3_kernel(const f16* __restrict__ X3, float* __restrict__ OUT) {
    const int base = (blockIdx.x * 256 + threadIdx.x) * 8;
    half8 x3 = *(const half8*)&X3[base];
    float4v o0 = *(const float4v*)&OUT[base];
    float4v o1 = *(const float4v*)&OUT[base + 4];
    #pragma unroll
    for (int j = 0; j < 4; ++j) o0[j] += (float)x3[j] * (1.0f / 6.0f);
    #pragma unroll
    for (int j = 0; j < 4; ++j) o1[j] += (float)x3[j + 4] * (1.0f / 6.0f);
    *(float4v*)&OUT[base] = o0;
    *(float4v*)&OUT[base + 4] = o1;
}

// Degree-4 Taylor, direct form: OUT = I + X + X2/2 + X3/6 + X4/24.
//   PHASE 0 (grid 512): unit u = partial X2 over k in [u*1024,(u+1)*1024),
//     A=BT=X (NEGOUT, X skew); writes P_u (f16, F0/F1).
//   PHASE 1 (grid 512): unit 0: X3 = X2*X (BT=X, NEGOUT) -> F0 (f16).
//     unit 1: X4 = X2*X2 (BT=X2, symmetric) -> OUT = I + X + X2/2 + v/24 (fp32).
// Core (R6-proven): 512 thr = 8 waves, 128x128 tile, BK=64, intra-block
// split-K-2 (waves 0-3 k-low half, 4-7 k-high), wave tile 64x64 (4x4
// 16x16x32 frags), double-buffered LDS staging via global_load_lds (16B,
// XOR-swizzled). K-merge done in TWO rounds through 2 x 17KB LDS slots so
// total LDS = 64KB -> 2 blocks/CU co-resident (the round-11 change).
template <int PHASE>
__global__ __launch_bounds__(512, 4) void gemm_ps_kernel(
    const f16* __restrict__ Ap, const f16* __restrict__ Bta,
    const f16* __restrict__ Btb,
    const f16* __restrict__ Xp, const f16* __restrict__ X2p,
    f16* __restrict__ F0, f16* __restrict__ F1, float* __restrict__ OUT) {
    constexpr int KITERS = (PHASE == 0) ? 16 : 32;
    constexpr int PLH = 128 * 64;          // halfs per plane-tile (16 KB)
    constexpr int BUFH = 2 * PLH;          // halfs per dbuf buffer (32 KB)
    __shared__ __align__(16) char smem_raw[2 * BUFH * 2];  // 64 KB total

    const int tid = threadIdx.x;
    const int wave = tid >> 6, lane = tid & 63;
    const int grp = wave >> 2, w4 = wave & 3;   // grp = K half
    const int wr = w4 >> 1, wc = w4 & 1;
    const int l15 = lane & 15, qq = lane >> 4;

    int bid = blockIdx.x;
    const int unit = bid >> 8;
    bid &= 255;
    const f16* Bp = (PHASE == 1 && unit == 1) ? Btb : Bta;
    const int kb = (PHASE == 0) ? (unit << 10) : 0;

    // XCD swizzle: 8x4 tile rectangle per XCD (bid&7 round-robin assumed)
    const int xcd = bid & 7, li = bid >> 3;
    const int by = (xcd >> 2) * 8 + (li >> 2);
    const int bx = (xcd & 3) * 4 + (li & 3);
    const int rowBase = by * 128, colBase = bx * 128;

    // Staging: 2 planes x 1024 16B-chunks; thread covers c = r*512+tid.
    // Row m, physical chunk sp holds logical k-chunk sl = sp ^ (m&7).
    const f16* gsrc[2][2];
    int ldsoff[2];
    #pragma unroll
    for (int r = 0; r < 2; ++r) {
        const int c = r * 512 + tid;
        const int m = c >> 3, sp = c & 7;
        const int sl = sp ^ (m & 7);
        ldsoff[r] = c * 8;
        gsrc[0][r] = Ap + (size_t)(rowBase + m) * NM + kb + sl * 8;
        gsrc[1][r] = Bp + (size_t)(colBase + m) * NM + kb + sl * 8;
    }

    // Fragment LDS offsets (halfs); this wave reads k-chunk grp*4+qq.
    int offA[4], offB[4];
    #pragma unroll
    for (int r = 0; r < 4; ++r) {
        const int m = wr * 64 + r * 16 + l15;
        offA[r] = (m * 8 + ((grp * 4 + qq) ^ (m & 7))) * 8;
        const int n = wc * 64 + r * 16 + l15;
        offB[r] = PLH + (n * 8 + ((grp * 4 + qq) ^ (n & 7))) * 8;
    }

    float4v acc[4][4];
    #pragma unroll
    for (int r = 0; r < 4; ++r)
        #pragma unroll
        for (int c = 0; c < 4; ++c)
            acc[r][c] = (float4v){0.f, 0.f, 0.f, 0.f};

    auto stage = [&](int buf) {
        f16* base = (f16*)smem_raw + buf * BUFH;
        #pragma unroll
        for (int p = 0; p < 2; ++p)
            #pragma unroll
            for (int r = 0; r < 2; ++r) {
                __builtin_amdgcn_global_load_lds(
                    (const __attribute__((address_space(1))) void*)gsrc[p][r],
                    (__attribute__((address_space(3))) void*)(uintptr_t)(base + p * PLH + ldsoff[r]),
                    16, 0, 0);
                gsrc[p][r] += 64;
            }
    };

    stage(0);
    for (int k = 0; k < KITERS; ++k) {
        __syncthreads();
        if (k < KITERS - 1) stage((k + 1) & 1);
        const f16* base = (const f16*)smem_raw + (k & 1) * BUFH;
        half8 ah[4], bh[4];
        #pragma unroll
        for (int r = 0; r < 4; ++r) ah[r] = *(const half8*)&base[offA[r]];
        #pragma unroll
        for (int c = 0; c < 4; ++c) bh[c] = *(const half8*)&base[offB[c]];
        #pragma unroll
        for (int r = 0; r < 4; ++r)
            #pragma unroll
            for (int c = 0; c < 4; ++c)
                acc[r][c] = __builtin_amdgcn_mfma_f32_16x16x32_f16(ah[r], bh[c], acc[r][c], 0, 0, 0);
    }

    // Two-round K-merge: pairs (w, w+4) share w4; 2 slots of 4352 floats (34.8 KB).
    float* mbuf = (float*)smem_raw;
    auto dump = [&](int slot) {
        float* base = mbuf + (size_t)slot * 4352;
        #pragma unroll
        for (int r = 0; r < 4; ++r)
            #pragma unroll
            for (int c = 0; c < 4; ++c)
                *(float4v*)&base[(c * 16 + l15) * 68 + r * 16 + qq * 4] = acc[r][c];
    };
    auto addm = [&](int slot) {
        const float* base = mbuf + (size_t)slot * 4352;
        #pragma unroll
        for (int r = 0; r < 4; ++r)
            #pragma unroll
            for (int c = 0; c < 4; ++c)
                acc[r][c] += *(const float4v*)&base[(c * 16 + l15) * 68 + r * 16 + qq * 4];
    };
    __syncthreads();                       // staging LDS dead
    if (wave == 4 || wave == 5) dump(wave - 4);
    __syncthreads();
    if (wave == 0 || wave == 1) addm(wave);
    __syncthreads();
    if (wave == 6 || wave == 7) dump(wave - 6);
    __syncthreads();
    if (wave == 2 || wave == 3) addm(wave - 2);

    if (wave < 4) {
        // C/D layout: col = lane&15, row = (lane>>4)*4 + reg
        #pragma unroll
        for (int r = 0; r < 4; ++r)
            #pragma unroll
            for (int c = 0; c < 4; ++c)
                #pragma unroll
                for (int g = 0; g < 4; ++g) {
                    const int row = rowBase + wr * 64 + r * 16 + qq * 4 + g;
                    const int col = colBase + wc * 64 + c * 16 + l15;
                    const size_t off = (size_t)row * NM + col;
                    float v = acc[r][c][g];
                    if (PHASE == 0) {
                        v = -v;  // A*X^T = -A*X for skew X
                        (unit ? F1 : F0)[off] = (f16)v;
                    } else if (unit == 0) {
                        v = -v;  // X3 = -(X2 * X^T)
                        F0[off] = (f16)v;
                    } else {
                        const float x = (float)Xp[off];
                        const float x2 = (float)X2p[off];
                        float o = x + 0.5f * x2 + v * (1.0f / 24.0f);
                        if (row == col) o += 1.0f;
                        OUT[off] = o;
                    }
                }
    }
}

extern "C" void kernel_launch(void* const* d_in, const int* in_sizes, int n_in,
                              void* d_out, int out_size, void* d_ws, size_t ws_size,
                              hipStream_t stream) {
    const float* A = (const float*)d_in[0];
    float* out = (float*)d_out;
    const size_t NN = (size_t)NM * NM;

    // ws: 4 f16 planes (33.6 MB). d_out holds only the fp32 result.
    f16* X  = (f16*)d_ws;      // W0
    f16* P1 = X + NN;          // W1: phase-A partial -> X2 (in-place)
    f16* P2 = P1 + NN;         // W2: phase-A partial
    f16* X3 = P2 + NN;         // W3
    f16* X2 = P1;

    dim3 tb(32, 8);
    dim3 tg(NM / 32, NM / 32);

    // OUT = I + X + X2/2 + X3/6 + X4/24  (degree-4 Taylor; delocalized
    // truncation ~9e-4 << 1.66e-2; all GEMMs 1-term f16, no amplification).
    // 1) X = A - A^T
    skew_f16_kernel<<<tg, tb, 0, stream>>>(A, X);
    // 2) Phase A: K-split X2 partials, 512 independent blocks
    gemm_ps_kernel<0><<<512, 512, 0, stream>>>(X, X, nullptr, nullptr, nullptr, P1, P2, nullptr);
    // 3) X2 = P1 + P2 (in-place over P1)
    sum2_kernel<<<NN / 2048, 256, 0, stream>>>(P1, P2);
    // 4) Phase B: unit0 X3 = X2*X -> W3; unit1 X4 = X2*X2 -> OUT (fused fp32 epilogue)
    gemm_ps_kernel<1><<<512, 512, 0, stream>>>(X2, X, X2, X, X2, X3, nullptr, out);
    // 5) OUT += X3/6
    addx3_kernel<<<NN / 2048, 256, 0, stream>>>(X3, out);
}